// Round 7
// baseline (188.026 us; speedup 1.0000x reference)
//
#include <hip/hip_runtime.h>
#include <cstddef>

// QSelfAttention MI355X round 7: software-pipelined flash chunk loop.
//   flash: q64 x c256 block (grid 512 unchanged, 2 blocks/CU), 32 chunks of
//   32 keys, K/V DOUBLE-BUFFERED in LDS (46 KB of the free 80 KB budget),
//   2 barriers/chunk. DMA(t+1) issued right after barrier B(t); its vmcnt
//   drain lands at barrier C(t), covered by S+exp compute. Work composition
//   (MFMA count, DMA bytes, grid) identical to r4/r6 flash.
//   prep/k1/k4 unchanged from round 6 (q pre-scaled by 0.125*log2e -> exp2).

typedef unsigned short ushort_t;
typedef __attribute__((ext_vector_type(8))) short bf16x8;
typedef __attribute__((ext_vector_type(4))) float f32x4;

#define QSCALE 0.18033688011112042f  // 0.125 * log2(e)

__device__ __forceinline__ ushort_t f2bf(float f) {
  unsigned int x = __float_as_uint(f);
  unsigned int r = (x + 0x7fffu + ((x >> 16) & 1u)) >> 16;
  return (ushort_t)r;
}

__device__ __forceinline__ void gload16(const ushort_t* g, ushort_t* l) {
  __builtin_amdgcn_global_load_lds(
      (const __attribute__((address_space(1))) void*)g,
      (__attribute__((address_space(3))) void*)l, 16, 0, 0);
}

// ---------------------------------------------------------------------------
// Core NT GEMM: D[M][N] = A[M][K] * B[N][K]^T, bf16 in, fp32 acc.
// TM in {64,128}, TN=128, BK=64, 256 threads (4 waves, 2x2 wave grid).
template <int TM>
__device__ __forceinline__ void gemm_core(
    const ushort_t* __restrict__ A, int lda,
    const ushort_t* __restrict__ B, int ldb,
    int K, int m0, int n0,
    ushort_t* As, ushort_t* Bs, f32x4 (*acc)[4])
{
  constexpr int MT  = TM / 32;
  constexpr int WTM = TM / 2;
  const int t = threadIdx.x;
  const int lane = t & 63, quad = lane >> 4, l15 = lane & 15;
  const int w = t >> 6, wm = w >> 1, wn = w & 1;
  const int rr = (lane >> 3) & 7;
  const int gg = (lane & 7) ^ rr;

  #pragma unroll
  for (int i = 0; i < MT; ++i)
    #pragma unroll
    for (int j = 0; j < 4; ++j) acc[i][j] = (f32x4){0.f, 0.f, 0.f, 0.f};

  for (int k0 = 0; k0 < K; k0 += 64) {
    #pragma unroll
    for (int i = 0; i < TM / 32; ++i) {
      const int mrow = w * (TM / 4) + i * 8;
      gload16(A + (size_t)(m0 + mrow + rr) * lda + k0 + gg * 8, As + mrow * 64);
    }
    #pragma unroll
    for (int i = 0; i < 4; ++i) {
      const int mrow = w * 32 + i * 8;
      gload16(B + (size_t)(n0 + mrow + rr) * ldb + k0 + gg * 8, Bs + mrow * 64);
    }
    __syncthreads();
    #pragma unroll
    for (int kk = 0; kk < 2; ++kk) {
      const int gq = kk * 4 + quad;
      const int sg = (gq ^ (l15 & 7)) * 8;
      bf16x8 af[MT], bfr[4];
      #pragma unroll
      for (int i = 0; i < MT; ++i)
        af[i] = *(const bf16x8*)(As + (wm * WTM + i * 16 + l15) * 64 + sg);
      #pragma unroll
      for (int j = 0; j < 4; ++j)
        bfr[j] = *(const bf16x8*)(Bs + (wn * 64 + j * 16 + l15) * 64 + sg);
      #pragma unroll
      for (int i = 0; i < MT; ++i)
        #pragma unroll
        for (int j = 0; j < 4; ++j)
          acc[i][j] = __builtin_amdgcn_mfma_f32_16x16x32_bf16(
              af[i], bfr[j], acc[i][j], 0, 0, 0);
    }
    __syncthreads();
  }
}

template <int TM, class F>
__device__ __forceinline__ void store_bf16(
    ushort_t* lds, ushort_t* __restrict__ out, int ldo, int m0, int n0,
    f32x4 (*acc)[4], F f)
{
  constexpr int MT = TM / 32, WTM = TM / 2, SI = TM / 16;
  const int t = threadIdx.x;
  const int lane = t & 63, quad = lane >> 4, l15 = lane & 15;
  const int w = t >> 6, wm = w >> 1, wn = w & 1;
  #pragma unroll
  for (int i = 0; i < MT; ++i)
    #pragma unroll
    for (int j = 0; j < 4; ++j)
      #pragma unroll
      for (int r = 0; r < 4; ++r) {
        const int rl = wm * WTM + i * 16 + quad * 4 + r;
        const int cl = wn * 64 + j * 16 + l15;
        lds[rl * 136 + cl] = f2bf(f(i, j, r, rl, cl, acc[i][j][r]));
      }
  __syncthreads();
  #pragma unroll
  for (int i = 0; i < SI; ++i) {
    const int s = i * 256 + t, m = s >> 4, g = s & 15;
    const uint4 v = *(const uint4*)(lds + m * 136 + g * 8);
    *(uint4*)(out + (size_t)(m0 + m) * ldo + n0 + g * 8) = v;
  }
}

// ---------------------------------------------------------------------------
// prep: x[b][c][n] fp32 -> xbfT[b][n][c] bf16 (64x64 tiles, blockIdx.y<8)
//       + all weight fp32->bf16 conversions (blockIdx.y==8)
__global__ __launch_bounds__(256) void prep_x(
    const float* __restrict__ x,
    const float* __restrict__ Wq, const float* __restrict__ Wk,
    const float* __restrict__ Wv, const float* __restrict__ Wo,
    ushort_t* __restrict__ xbfT, ushort_t* __restrict__ Wqk,
    ushort_t* __restrict__ Wvb, ushort_t* __restrict__ Wob)
{
  __shared__ float T[64][65];
  const int t = threadIdx.x;
  if (blockIdx.y == 8) {
    const int id = blockIdx.z * 16 + blockIdx.x;
    #pragma unroll
    for (int p = 0; p < 5; ++p) {
      const int s = p * 256 + t;
      if (s < 1152) {
        const int u = id * 1152 + s;
        const int e = u * 2;
        float f0, f1;
        if (e < 32768)       { f0 = Wq[e];         f1 = Wq[e + 1]; }
        else if (e < 65536)  { f0 = Wk[e - 32768]; f1 = Wk[e - 32767]; }
        else if (e < 327680) { f0 = Wv[e - 65536]; f1 = Wv[e - 65535]; }
        else                 { f0 = Wo[e - 327680]; f1 = Wo[e - 327679]; }
        const unsigned pk = (unsigned)f2bf(f0) | ((unsigned)f2bf(f1) << 16);
        if (e < 65536)       *((unsigned*)Wqk + u) = pk;
        else if (e < 327680) *((unsigned*)Wvb + (u - 32768)) = pk;
        else                 *((unsigned*)Wob + (u - 163840)) = pk;
      }
    }
    return;
  }
  const int b = blockIdx.z, c0 = blockIdx.y * 64, n0 = blockIdx.x * 64;
  const float* xb = x + ((size_t)b * 512 + c0) * 1024 + n0;
  const int nj = t & 63, ci0 = t >> 6;
  #pragma unroll
  for (int p = 0; p < 16; ++p) {
    const int ci = p * 4 + ci0;
    T[ci][nj] = xb[(size_t)ci * 1024 + nj];
  }
  __syncthreads();
  const int c2 = (t & 31) * 2, nr0 = t >> 5;
  #pragma unroll
  for (int p = 0; p < 8; ++p) {
    const int nr = p * 8 + nr0;
    const unsigned lo = f2bf(T[c2][nr]), hi = f2bf(T[c2 + 1][nr]);
    *(unsigned*)&xbfT[((size_t)b * 1024 + n0 + nr) * 512 + c0 + c2] =
        lo | (hi << 16);
  }
}

// ---------------------------------------------------------------------------
// k1 fused: blocks 0..511 -> V projection (vt2[b][c][n], TM=128);
//           blocks 512..767 -> QK projection (qkt[b][n][128], TM=64).
// Q columns (0..63) pre-scaled by QSCALE so flash uses bare exp2f.
__global__ __launch_bounds__(256) void k1_fused(
    const ushort_t* __restrict__ xbfT, const ushort_t* __restrict__ Wqk,
    const ushort_t* __restrict__ Wvb,
    const float* __restrict__ bq, const float* __restrict__ bk,
    const float* __restrict__ bv,
    ushort_t* __restrict__ qkt, ushort_t* __restrict__ vt2)
{
  __shared__ __align__(16) ushort_t lds[17408];
  const int bid = blockIdx.x;
  const int t = threadIdx.x, lane = t & 63, quad = lane >> 4, l15 = lane & 15;
  const int w = t >> 6, wm = w >> 1, wn = w & 1;
  if (bid < 512) {
    const int b = bid >> 5, my = (bid >> 3) & 3, nx = bid & 7;
    const int m0 = my * 128, n0 = nx * 128;
    f32x4 acc[4][4];
    gemm_core<128>(Wvb, 512, xbfT + (size_t)b * 524288, 512, 512, m0, n0,
                   lds, lds + 128 * 64, acc);
    float br[4][4];
    #pragma unroll
    for (int i = 0; i < 4; ++i)
      #pragma unroll
      for (int r = 0; r < 4; ++r)
        br[i][r] = bv[m0 + wm * 64 + i * 16 + quad * 4 + r];
    store_bf16<128>(lds, vt2 + (size_t)b * 524288, 1024, m0, n0, acc,
        [&](int i, int, int r, int, int, float v) { return v + br[i][r]; });
  } else {
    const int id = bid - 512, b = id >> 4, my = id & 15;
    const int m0 = my * 64;
    f32x4 acc[2][4];
    gemm_core<64>(xbfT + (size_t)b * 524288, 512, Wqk, 512, 512, m0, 0,
                  lds, lds + 64 * 64, acc);
    float bc[4], qs[4];
    #pragma unroll
    for (int j = 0; j < 4; ++j) {
      const int col = wn * 64 + j * 16 + l15;
      bc[j] = (col < 64) ? bq[col] : bk[col - 64];
      qs[j] = (col < 64) ? QSCALE : 1.0f;
    }
    store_bf16<64>(lds, qkt + (size_t)b * 131072, 128, m0, 0, acc,
        [&](int, int j, int, int, int, float v) { return (v + bc[j]) * qs[j]; });
  }
}

// ---------------------------------------------------------------------------
// flash: per block (b, 64 q-rows m0, 256 c-cols c0); 32 chunks of 32 keys,
// K/V double-buffered, 2 barriers/chunk, DMA(t+1) issued after barrier B(t).
// LDS ush: Ks[2][32*64]@0 | Vs[2][256*32]@4096 | Ps[64*40]@20480 = 46 KB.
__global__ __launch_bounds__(256) void flash_attn(
    const ushort_t* __restrict__ qkt, const ushort_t* __restrict__ vt2,
    ushort_t* __restrict__ o1)
{
  __shared__ __align__(16) ushort_t buf[23040];
  __shared__ float lsum[64][2];
  ushort_t* Ps = buf + 20480;   // stride 40

  const int t = threadIdx.x;
  const int lane = t & 63, quad = lane >> 4, l15 = lane & 15;
  const int w = t >> 6, wm = w >> 1, wn = w & 1;
  const int rr = (lane >> 3) & 7, gg = (lane & 7) ^ rr;  // K/Q staging map
  const int vrow = lane >> 2, vgrp = lane & 3;           // V staging map

  const int b = blockIdx.z, m0 = blockIdx.y * 64, c0 = blockIdx.x * 256;
  const ushort_t* qb = qkt + (size_t)b * 131072;  // [n][128]: q 0..63, k 64..127
  const ushort_t* vb = vt2 + (size_t)b * 524288;  // [c][1024]

  // ---- stage Q (64x64, XOR-swizzled) into Vs0 region, pull to registers
  {
    ushort_t* qstage = buf + 4096;
    #pragma unroll
    for (int i = 0; i < 2; ++i) {
      const int mrow = w * 16 + i * 8;
      gload16(qb + (size_t)(m0 + mrow + rr) * 128 + gg * 8, qstage + mrow * 64);
    }
    __syncthreads();
  }
  bf16x8 af_q[2][2];
  #pragma unroll
  for (int kk = 0; kk < 2; ++kk) {
    const int sg = ((kk * 4 + quad) ^ (l15 & 7)) * 8;
    #pragma unroll
    for (int i = 0; i < 2; ++i)
      af_q[i][kk] =
          *(const bf16x8*)(buf + 4096 + (wm * 32 + i * 16 + l15) * 64 + sg);
  }
  __syncthreads();  // Q reads done before DMA(0) overwrites Vs0

  f32x4 accO[2][8];
  #pragma unroll
  for (int i = 0; i < 2; ++i)
    #pragma unroll
    for (int j = 0; j < 8; ++j) accO[i][j] = (f32x4){0.f, 0.f, 0.f, 0.f};
  float rsum[2][4] = {{0.f, 0.f, 0.f, 0.f}, {0.f, 0.f, 0.f, 0.f}};

  // ---- preissue DMA(0) into buffer 0
  {
    ushort_t* Kb = buf;            // Ks[0]
    ushort_t* Vb = buf + 4096;     // Vs[0]
    gload16(qb + (size_t)(w * 8 + rr) * 128 + 64 + gg * 8, Kb + w * 8 * 64);
    #pragma unroll
    for (int i = 0; i < 4; ++i) {
      const int crow = w * 64 + i * 16;
      gload16(vb + (size_t)(c0 + crow + vrow) * 1024 + vgrp * 8,
              Vb + crow * 32);
    }
  }

  #pragma unroll 2
  for (int tch = 0; tch < 32; ++tch) {
    ushort_t* Kb = buf + (tch & 1) * 2048;
    ushort_t* Vb = buf + 4096 + (tch & 1) * 8192;
    __syncthreads();  // B(t): DMA(t) landed (drained at C(t-1), cheap here)

    if (tch < 31) {   // issue DMA(t+1) into the other buffer
      const int kt1 = (tch + 1) * 32;
      ushort_t* Kn = buf + ((tch + 1) & 1) * 2048;
      ushort_t* Vn = buf + 4096 + ((tch + 1) & 1) * 8192;
      gload16(qb + (size_t)(kt1 + w * 8 + rr) * 128 + 64 + gg * 8,
              Kn + w * 8 * 64);
      #pragma unroll
      for (int i = 0; i < 4; ++i) {
        const int crow = w * 64 + i * 16;
        gload16(vb + (size_t)(c0 + crow + vrow) * 1024 + kt1 + vgrp * 8,
                Vn + crow * 32);
      }
    }

    // S-phase: q 64 (wm,i) x keys 32 (wn,l15), K=64 (kc)
    f32x4 accS[2];
    #pragma unroll
    for (int i = 0; i < 2; ++i) accS[i] = (f32x4){0.f, 0.f, 0.f, 0.f};
    #pragma unroll
    for (int kk = 0; kk < 2; ++kk) {
      const int sg = ((kk * 4 + quad) ^ (l15 & 7)) * 8;
      const bf16x8 bk_ = *(const bf16x8*)(Kb + (wn * 16 + l15) * 64 + sg);
      #pragma unroll
      for (int i = 0; i < 2; ++i)
        accS[i] = __builtin_amdgcn_mfma_f32_16x16x32_bf16(
            af_q[i][kk], bk_, accS[i], 0, 0, 0);
    }
    // exp2 (scale folded into Q), row-sum partials, Ps write
    #pragma unroll
    for (int i = 0; i < 2; ++i)
      #pragma unroll
      for (int r = 0; r < 4; ++r) {
        const float e = exp2f(accS[i][r]);
        rsum[i][r] += e;
        Ps[(wm * 32 + i * 16 + quad * 4 + r) * 40 + wn * 16 + l15] = f2bf(e);
      }
    __syncthreads();  // C(t): Ps visible; drains DMA(t+1) (covered by S+exp)

    // PV-phase: O[64][256] += Ps[64][32] . Vs[256][32]^T  (K=32, one step)
    bf16x8 ap[2], bv_[8];
    #pragma unroll
    for (int i = 0; i < 2; ++i)
      ap[i] = *(const bf16x8*)(Ps + (wm * 32 + i * 16 + l15) * 40 + quad * 8);
    #pragma unroll
    for (int j = 0; j < 8; ++j)
      bv_[j] = *(const bf16x8*)(Vb + (wn * 128 + j * 16 + l15) * 32 + quad * 8);
    #pragma unroll
    for (int i = 0; i < 2; ++i)
      #pragma unroll
      for (int j = 0; j < 8; ++j)
        accO[i][j] = __builtin_amdgcn_mfma_f32_16x16x32_bf16(
            ap[i], bv_[j], accO[i][j], 0, 0, 0);
  }

  // finish row sums: reduce over the 16 key-lanes, combine the two wn waves
  #pragma unroll
  for (int i = 0; i < 2; ++i)
    #pragma unroll
    for (int r = 0; r < 4; ++r) {
      float s = rsum[i][r];
      #pragma unroll
      for (int d = 1; d < 16; d <<= 1) s += __shfl_xor(s, d, 16);
      if (l15 == 0) lsum[wm * 32 + i * 16 + quad * 4 + r][wn] = s;
    }
  __syncthreads();  // last PV's LDS reads done before bounce overwrite

  ushort_t* fl_b = buf;  // [64][264] = 16896 ush, fits below Ps
  #pragma unroll
  for (int i = 0; i < 2; ++i)
    #pragma unroll
    for (int r = 0; r < 4; ++r) {
      const int row = wm * 32 + i * 16 + quad * 4 + r;
      const float inv = 1.0f / (lsum[row][0] + lsum[row][1]);
      #pragma unroll
      for (int j = 0; j < 8; ++j)
        fl_b[row * 264 + wn * 128 + j * 16 + l15] = f2bf(accO[i][j][r] * inv);
    }
  __syncthreads();
  #pragma unroll
  for (int p = 0; p < 8; ++p) {
    const int s = p * 256 + t, m = s >> 5, g = s & 31;
    const uint4 v = *(const uint4*)(fl_b + m * 264 + g * 8);
    *(uint4*)(o1 + ((size_t)b * 1024 + m0 + m) * 512 + c0 + g * 8) = v;
  }
}

// ---------------------------------------------------------------------------
// K4: out[b][c][n] = g*(Wo @ o1^T + bo) + x.  M=c(512) N=n(1024) K=v(512)
__global__ __launch_bounds__(256) void k4_proj(
    const ushort_t* __restrict__ Wob, const ushort_t* __restrict__ o1,
    const float* __restrict__ bo, const float* __restrict__ gamma,
    const float* __restrict__ x, float* __restrict__ out)
{
  __shared__ __align__(16) ushort_t lds[128 * 136];
  const int b = blockIdx.z, m0 = blockIdx.y * 128, n0 = blockIdx.x * 128;
  f32x4 acc[4][4];
  gemm_core<128>(Wob, 512, o1 + (size_t)b * 524288, 512, 512, m0, n0,
                 lds, lds + 128 * 64, acc);
  const int t = threadIdx.x, lane = t & 63, quad = lane >> 4, l15 = lane & 15;
  const int w = t >> 6, wm = w >> 1, wn = w & 1;
  const float g = gamma[0];
  float br[4][4];
  #pragma unroll
  for (int i = 0; i < 4; ++i)
    #pragma unroll
    for (int r = 0; r < 4; ++r)
      br[i][r] = bo[m0 + wm * 64 + i * 16 + quad * 4 + r];
  float* fl = (float*)lds;  // 64 rows x 132 f stride
  #pragma unroll
  for (int h = 0; h < 2; ++h) {
    if (wm == h) {
      #pragma unroll
      for (int i = 0; i < 4; ++i)
        #pragma unroll
        for (int j = 0; j < 4; ++j)
          #pragma unroll
          for (int r = 0; r < 4; ++r)
            fl[(i * 16 + quad * 4 + r) * 132 + wn * 64 + j * 16 + l15] =
                g * (acc[i][j][r] + br[i][r]);
    }
    __syncthreads();
    #pragma unroll
    for (int i2 = 0; i2 < 8; ++i2) {
      const int s = i2 * 256 + t, m = s >> 5, c4 = s & 31;
      f32x4 v = *(const f32x4*)(fl + m * 132 + c4 * 4);
      const size_t gi = ((size_t)b * 512 + m0 + h * 64 + m) * 1024 + n0 + c4 * 4;
      const f32x4 xr = *(const f32x4*)(x + gi);
      v += xr;
      *(f32x4*)(out + gi) = v;
    }
    __syncthreads();
  }
}

// ---------------------------------------------------------------------------
extern "C" void kernel_launch(void* const* d_in, const int* in_sizes, int n_in,
                              void* d_out, int out_size, void* d_ws, size_t ws_size,
                              hipStream_t stream) {
  const float* x     = (const float*)d_in[0];
  const float* Wq    = (const float*)d_in[1];
  const float* bq    = (const float*)d_in[2];
  const float* Wk    = (const float*)d_in[3];
  const float* bk    = (const float*)d_in[4];
  const float* Wv    = (const float*)d_in[5];
  const float* bv    = (const float*)d_in[6];
  const float* Wo    = (const float*)d_in[7];
  const float* bo    = (const float*)d_in[8];
  const float* gamma = (const float*)d_in[9];
  float* out = (float*)d_out;

  char* wsp = (char*)d_ws;
  ushort_t* xbfT   = (ushort_t*)wsp;  wsp += (size_t)16 * 1024 * 512 * 2;  // 16 MB
  ushort_t* Wqk_bf = (ushort_t*)wsp;  wsp += (size_t)128 * 512 * 2;
  ushort_t* Wv_bf  = (ushort_t*)wsp;  wsp += (size_t)512 * 512 * 2;
  ushort_t* Wo_bf  = (ushort_t*)wsp;  wsp += (size_t)512 * 512 * 2;
  ushort_t* qkt    = (ushort_t*)wsp;  wsp += (size_t)16 * 1024 * 128 * 2;  // 4 MB
  ushort_t* vt2    = (ushort_t*)wsp;  wsp += (size_t)16 * 512 * 1024 * 2;  // 16 MB
  ushort_t* o1     = xbfT;  // xbfT dead after k1; reuse for o1

  prep_x    <<<dim3(16, 9, 16), 256, 0, stream>>>(x, Wq, Wk, Wv, Wo,
                                                  xbfT, Wqk_bf, Wv_bf, Wo_bf);
  k1_fused  <<<768, 256, 0, stream>>>(xbfT, Wqk_bf, Wv_bf, bq, bk, bv, qkt, vt2);
  flash_attn<<<dim3(2, 16, 16), 256, 0, stream>>>(qkt, vt2, o1);
  k4_proj   <<<dim3(8, 4, 16), 256, 0, stream>>>(Wo_bf, o1, bo, gamma, x, out);
}

// Round 8
// 184.036 us; speedup vs baseline: 1.0217x; 1.0217x over previous
//
#include <hip/hip_runtime.h>
#include <cstddef>

// QSelfAttention MI355X round 8: r6 structure + VALU slimming.
// Post-mortem r6/r7: VALU (44k cyc/CU) > MFMA (24k cyc/CU) in flash — the
// hand-rolled RNE f2bf (~5 ops) dominated. This round: truncation f2bf_t
// (1 op) on all hot paths, v_perm_b32 pair-packing in prep (1 op / 2 vals).
// Flash geometry/barriers byte-identical to r6 (best variant, 48.4 us).
//   prep  : x transpose->bf16 + weight conversions
//   k1    : QK projection (TM=64, q pre-scaled by 0.125*log2e) + V (TM=128)
//   flash : q64 x c256, 16 chunks x 64 keys, Q in regs, exp2, 3 barriers
//   k4    : Wo proj + gamma*(.)+x residual epilogue (exact fp32)

typedef unsigned short ushort_t;
typedef __attribute__((ext_vector_type(8))) short bf16x8;
typedef __attribute__((ext_vector_type(4))) float f32x4;

#define QSCALE 0.18033688011112042f  // 0.125 * log2(e)

// truncating f32->bf16: 1 VALU op (intermediates only; tolerance ~2^-8 ok)
__device__ __forceinline__ ushort_t f2bf_t(float f) {
  return (ushort_t)(__float_as_uint(f) >> 16);
}
// pack 2 f32 -> 2 bf16 in one dword: single v_perm_b32
__device__ __forceinline__ unsigned pk2bf(float lo, float hi) {
  return __builtin_amdgcn_perm(__float_as_uint(hi), __float_as_uint(lo),
                               0x07060302u);
}

__device__ __forceinline__ void gload16(const ushort_t* g, ushort_t* l) {
  __builtin_amdgcn_global_load_lds(
      (const __attribute__((address_space(1))) void*)g,
      (__attribute__((address_space(3))) void*)l, 16, 0, 0);
}

// ---------------------------------------------------------------------------
// Core NT GEMM: D[M][N] = A[M][K] * B[N][K]^T, bf16 in, fp32 acc.
// TM in {64,128}, TN=128, BK=64, 256 threads (4 waves, 2x2 wave grid).
template <int TM>
__device__ __forceinline__ void gemm_core(
    const ushort_t* __restrict__ A, int lda,
    const ushort_t* __restrict__ B, int ldb,
    int K, int m0, int n0,
    ushort_t* As, ushort_t* Bs, f32x4 (*acc)[4])
{
  constexpr int MT  = TM / 32;
  constexpr int WTM = TM / 2;
  const int t = threadIdx.x;
  const int lane = t & 63, quad = lane >> 4, l15 = lane & 15;
  const int w = t >> 6, wm = w >> 1, wn = w & 1;
  const int rr = (lane >> 3) & 7;
  const int gg = (lane & 7) ^ rr;

  #pragma unroll
  for (int i = 0; i < MT; ++i)
    #pragma unroll
    for (int j = 0; j < 4; ++j) acc[i][j] = (f32x4){0.f, 0.f, 0.f, 0.f};

  for (int k0 = 0; k0 < K; k0 += 64) {
    #pragma unroll
    for (int i = 0; i < TM / 32; ++i) {
      const int mrow = w * (TM / 4) + i * 8;
      gload16(A + (size_t)(m0 + mrow + rr) * lda + k0 + gg * 8, As + mrow * 64);
    }
    #pragma unroll
    for (int i = 0; i < 4; ++i) {
      const int mrow = w * 32 + i * 8;
      gload16(B + (size_t)(n0 + mrow + rr) * ldb + k0 + gg * 8, Bs + mrow * 64);
    }
    __syncthreads();
    #pragma unroll
    for (int kk = 0; kk < 2; ++kk) {
      const int gq = kk * 4 + quad;
      const int sg = (gq ^ (l15 & 7)) * 8;
      bf16x8 af[MT], bfr[4];
      #pragma unroll
      for (int i = 0; i < MT; ++i)
        af[i] = *(const bf16x8*)(As + (wm * WTM + i * 16 + l15) * 64 + sg);
      #pragma unroll
      for (int j = 0; j < 4; ++j)
        bfr[j] = *(const bf16x8*)(Bs + (wn * 64 + j * 16 + l15) * 64 + sg);
      #pragma unroll
      for (int i = 0; i < MT; ++i)
        #pragma unroll
        for (int j = 0; j < 4; ++j)
          acc[i][j] = __builtin_amdgcn_mfma_f32_16x16x32_bf16(
              af[i], bfr[j], acc[i][j], 0, 0, 0);
    }
    __syncthreads();
  }
}

template <int TM, class F>
__device__ __forceinline__ void store_bf16(
    ushort_t* lds, ushort_t* __restrict__ out, int ldo, int m0, int n0,
    f32x4 (*acc)[4], F f)
{
  constexpr int MT = TM / 32, WTM = TM / 2, SI = TM / 16;
  const int t = threadIdx.x;
  const int lane = t & 63, quad = lane >> 4, l15 = lane & 15;
  const int w = t >> 6, wm = w >> 1, wn = w & 1;
  #pragma unroll
  for (int i = 0; i < MT; ++i)
    #pragma unroll
    for (int j = 0; j < 4; ++j)
      #pragma unroll
      for (int r = 0; r < 4; ++r) {
        const int rl = wm * WTM + i * 16 + quad * 4 + r;
        const int cl = wn * 64 + j * 16 + l15;
        lds[rl * 136 + cl] = f2bf_t(f(i, j, r, rl, cl, acc[i][j][r]));
      }
  __syncthreads();
  #pragma unroll
  for (int i = 0; i < SI; ++i) {
    const int s = i * 256 + t, m = s >> 4, g = s & 15;
    const uint4 v = *(const uint4*)(lds + m * 136 + g * 8);
    *(uint4*)(out + (size_t)(m0 + m) * ldo + n0 + g * 8) = v;
  }
}

// ---------------------------------------------------------------------------
// prep: x[b][c][n] fp32 -> xbfT[b][n][c] bf16 (64x64 tiles, blockIdx.y<8)
//       + all weight fp32->bf16 conversions (blockIdx.y==8)
__global__ __launch_bounds__(256) void prep_x(
    const float* __restrict__ x,
    const float* __restrict__ Wq, const float* __restrict__ Wk,
    const float* __restrict__ Wv, const float* __restrict__ Wo,
    ushort_t* __restrict__ xbfT, ushort_t* __restrict__ Wqk,
    ushort_t* __restrict__ Wvb, ushort_t* __restrict__ Wob)
{
  __shared__ float T[64][65];
  const int t = threadIdx.x;
  if (blockIdx.y == 8) {
    const int id = blockIdx.z * 16 + blockIdx.x;
    #pragma unroll
    for (int p = 0; p < 5; ++p) {
      const int s = p * 256 + t;
      if (s < 1152) {
        const int u = id * 1152 + s;
        const int e = u * 2;
        float f0, f1;
        if (e < 32768)       { f0 = Wq[e];         f1 = Wq[e + 1]; }
        else if (e < 65536)  { f0 = Wk[e - 32768]; f1 = Wk[e - 32767]; }
        else if (e < 327680) { f0 = Wv[e - 65536]; f1 = Wv[e - 65535]; }
        else                 { f0 = Wo[e - 327680]; f1 = Wo[e - 327679]; }
        const unsigned pk = pk2bf(f0, f1);
        if (e < 65536)       *((unsigned*)Wqk + u) = pk;
        else if (e < 327680) *((unsigned*)Wvb + (u - 32768)) = pk;
        else                 *((unsigned*)Wob + (u - 163840)) = pk;
      }
    }
    return;
  }
  const int b = blockIdx.z, c0 = blockIdx.y * 64, n0 = blockIdx.x * 64;
  const float* xb = x + ((size_t)b * 512 + c0) * 1024 + n0;
  const int nj = t & 63, ci0 = t >> 6;
  #pragma unroll
  for (int p = 0; p < 16; ++p) {
    const int ci = p * 4 + ci0;
    T[ci][nj] = xb[(size_t)ci * 1024 + nj];
  }
  __syncthreads();
  const int c2 = (t & 31) * 2, nr0 = t >> 5;
  #pragma unroll
  for (int p = 0; p < 8; ++p) {
    const int nr = p * 8 + nr0;
    *(unsigned*)&xbfT[((size_t)b * 1024 + n0 + nr) * 512 + c0 + c2] =
        pk2bf(T[c2][nr], T[c2 + 1][nr]);
  }
}

// ---------------------------------------------------------------------------
// k1 fused: blocks 0..511 -> V projection (vt2[b][c][n], TM=128);
//           blocks 512..767 -> QK projection (qkt[b][n][128], TM=64).
// Q columns (0..63) pre-scaled by QSCALE so flash uses bare exp2f.
__global__ __launch_bounds__(256) void k1_fused(
    const ushort_t* __restrict__ xbfT, const ushort_t* __restrict__ Wqk,
    const ushort_t* __restrict__ Wvb,
    const float* __restrict__ bq, const float* __restrict__ bk,
    const float* __restrict__ bv,
    ushort_t* __restrict__ qkt, ushort_t* __restrict__ vt2)
{
  __shared__ __align__(16) ushort_t lds[17408];
  const int bid = blockIdx.x;
  const int t = threadIdx.x, lane = t & 63, quad = lane >> 4, l15 = lane & 15;
  const int w = t >> 6, wm = w >> 1, wn = w & 1;
  if (bid < 512) {
    const int b = bid >> 5, my = (bid >> 3) & 3, nx = bid & 7;
    const int m0 = my * 128, n0 = nx * 128;
    f32x4 acc[4][4];
    gemm_core<128>(Wvb, 512, xbfT + (size_t)b * 524288, 512, 512, m0, n0,
                   lds, lds + 128 * 64, acc);
    float br[4][4];
    #pragma unroll
    for (int i = 0; i < 4; ++i)
      #pragma unroll
      for (int r = 0; r < 4; ++r)
        br[i][r] = bv[m0 + wm * 64 + i * 16 + quad * 4 + r];
    store_bf16<128>(lds, vt2 + (size_t)b * 524288, 1024, m0, n0, acc,
        [&](int i, int, int r, int, int, float v) { return v + br[i][r]; });
  } else {
    const int id = bid - 512, b = id >> 4, my = id & 15;
    const int m0 = my * 64;
    f32x4 acc[2][4];
    gemm_core<64>(xbfT + (size_t)b * 524288, 512, Wqk, 512, 512, m0, 0,
                  lds, lds + 64 * 64, acc);
    float bc[4], qs[4];
    #pragma unroll
    for (int j = 0; j < 4; ++j) {
      const int col = wn * 64 + j * 16 + l15;
      bc[j] = (col < 64) ? bq[col] : bk[col - 64];
      qs[j] = (col < 64) ? QSCALE : 1.0f;
    }
    store_bf16<64>(lds, qkt + (size_t)b * 131072, 128, m0, 0, acc,
        [&](int, int j, int, int, int, float v) { return (v + bc[j]) * qs[j]; });
  }
}

// ---------------------------------------------------------------------------
// flash: per block (b, 64 q-rows m0, 256 c-cols c0); 16 chunks of 64 keys.
//   Q staged once through Ps region -> registers. Per chunk: S=Q.K^T ->
//   exp2 -> Ps (LDS bf16, trunc convert) -> O += Ps.V^T. Row sums in regs;
//   normalize + store o1[b][n][c] at end.
// LDS: Ks[64][64] | Vs[256][64] | Ps[64][72] = 50176 B (2 blocks/CU by grid).
__global__ __launch_bounds__(256) void flash_attn(
    const ushort_t* __restrict__ qkt, const ushort_t* __restrict__ vt2,
    ushort_t* __restrict__ o1)
{
  __shared__ __align__(16) ushort_t buf[25088];
  __shared__ float lsum[64][2];
  ushort_t* Ks = buf;            // 4096 ush
  ushort_t* Vs = buf + 4096;     // 16384 ush
  ushort_t* Ps = buf + 20480;    // 4608 ush (stride 72); Q-stage uses 4096

  const int t = threadIdx.x;
  const int lane = t & 63, quad = lane >> 4, l15 = lane & 15;
  const int w = t >> 6, wm = w >> 1, wn = w & 1;
  const int rr = (lane >> 3) & 7, gg = (lane & 7) ^ rr;

  const int b = blockIdx.z, m0 = blockIdx.y * 64, c0 = blockIdx.x * 256;
  const ushort_t* qb = qkt + (size_t)b * 131072;   // [n][128]: q 0..63, k 64..127
  const ushort_t* vb = vt2 + (size_t)b * 524288;   // [c][1024]

  // stage Q (64x64) into Ps region, pull fragments to registers
  #pragma unroll
  for (int i = 0; i < 2; ++i) {
    const int mrow = w * 16 + i * 8;
    gload16(qb + (size_t)(m0 + mrow + rr) * 128 + gg * 8, Ps + mrow * 64);
  }
  __syncthreads();
  bf16x8 af_q[2][2];
  #pragma unroll
  for (int kk = 0; kk < 2; ++kk) {
    const int sg = ((kk * 4 + quad) ^ (l15 & 7)) * 8;
    #pragma unroll
    for (int i = 0; i < 2; ++i)
      af_q[i][kk] = *(const bf16x8*)(Ps + (wm * 32 + i * 16 + l15) * 64 + sg);
  }

  f32x4 accO[2][8];
  #pragma unroll
  for (int i = 0; i < 2; ++i)
    #pragma unroll
    for (int j = 0; j < 8; ++j) accO[i][j] = (f32x4){0.f, 0.f, 0.f, 0.f};
  float rsum[2][4] = {{0.f, 0.f, 0.f, 0.f}, {0.f, 0.f, 0.f, 0.f}};

  // hoisted Ps write base: row base (wm*32 + quad*4), col base wn*32 + l15
  ushort_t* ps_w = Ps + (wm * 32 + quad * 4) * 72 + wn * 32 + l15;

  #pragma unroll 1
  for (int mc = 0; mc < 1024; mc += 64) {
    __syncthreads();  // A: prev chunk's LDS reads (and Q-frag reads) complete
    #pragma unroll
    for (int i = 0; i < 2; ++i) {
      const int mrow = w * 16 + i * 8;
      gload16(qb + (size_t)(mc + mrow + rr) * 128 + 64 + gg * 8, Ks + mrow * 64);
    }
    #pragma unroll
    for (int i = 0; i < 8; ++i) {
      const int mrow = w * 64 + i * 8;
      gload16(vb + (size_t)(c0 + mrow + rr) * 1024 + mc + gg * 8, Vs + mrow * 64);
    }
    __syncthreads();  // B: DMA drained

    // S-phase: rows wm*32+{0,16}, keys wn*32+{0,16}, K=64 (Q pre-scaled)
    f32x4 accS[2][2];
    #pragma unroll
    for (int i = 0; i < 2; ++i)
      #pragma unroll
      for (int j = 0; j < 2; ++j) accS[i][j] = (f32x4){0.f, 0.f, 0.f, 0.f};
    #pragma unroll
    for (int kk = 0; kk < 2; ++kk) {
      const int sg = ((kk * 4 + quad) ^ (l15 & 7)) * 8;
      bf16x8 bk_[2];
      #pragma unroll
      for (int j = 0; j < 2; ++j)
        bk_[j] = *(const bf16x8*)(Ks + (wn * 32 + j * 16 + l15) * 64 + sg);
      #pragma unroll
      for (int i = 0; i < 2; ++i)
        #pragma unroll
        for (int j = 0; j < 2; ++j)
          accS[i][j] = __builtin_amdgcn_mfma_f32_16x16x32_bf16(
              af_q[i][kk], bk_[j], accS[i][j], 0, 0, 0);
    }
    // exp2 (scale folded into Q) -> rsum partials -> Ps (trunc convert, 1 op)
    #pragma unroll
    for (int i = 0; i < 2; ++i)
      #pragma unroll
      for (int j = 0; j < 2; ++j)
        #pragma unroll
        for (int r = 0; r < 4; ++r) {
          const float e = exp2f(accS[i][j][r]);
          rsum[i][r] += e;
          ps_w[(i * 16 + r) * 72 + j * 16] = f2bf_t(e);
        }
    __syncthreads();  // C: Ps visible

    // PV-phase: O[64][256] += Ps[64][64] . Vs[256][64]^T
    #pragma unroll
    for (int kk = 0; kk < 2; ++kk) {
      const int gq = kk * 4 + quad;
      const int sgv = (gq ^ (l15 & 7)) * 8;
      bf16x8 ap[2], bv_[8];
      #pragma unroll
      for (int i = 0; i < 2; ++i)
        ap[i] = *(const bf16x8*)(Ps + (wm * 32 + i * 16 + l15) * 72 + gq * 8);
      #pragma unroll
      for (int j = 0; j < 8; ++j)
        bv_[j] = *(const bf16x8*)(Vs + (wn * 128 + j * 16 + l15) * 64 + sgv);
      #pragma unroll
      for (int i = 0; i < 2; ++i)
        #pragma unroll
        for (int j = 0; j < 8; ++j)
          accO[i][j] = __builtin_amdgcn_mfma_f32_16x16x32_bf16(
              ap[i], bv_[j], accO[i][j], 0, 0, 0);
    }
  }

  // finish row sums: reduce over the 16 key-lanes, combine the two wn waves
  #pragma unroll
  for (int i = 0; i < 2; ++i)
    #pragma unroll
    for (int r = 0; r < 4; ++r) {
      float s = rsum[i][r];
      #pragma unroll
      for (int d = 1; d < 16; d <<= 1) s += __shfl_xor(s, d, 16);
      if (l15 == 0) lsum[wm * 32 + i * 16 + quad * 4 + r][wn] = s;
    }
  __syncthreads();  // also: last PV's LDS reads done before fl_b overwrite

  ushort_t* fl_b = buf;  // [64][264] = 16896 ush, fits (Ps dead)
  #pragma unroll
  for (int i = 0; i < 2; ++i)
    #pragma unroll
    for (int r = 0; r < 4; ++r) {
      const int row = wm * 32 + i * 16 + quad * 4 + r;
      const float inv = 1.0f / (lsum[row][0] + lsum[row][1]);
      #pragma unroll
      for (int j = 0; j < 8; ++j)
        fl_b[row * 264 + wn * 128 + j * 16 + l15] = f2bf_t(accO[i][j][r] * inv);
    }
  __syncthreads();
  #pragma unroll
  for (int p = 0; p < 8; ++p) {
    const int s = p * 256 + t, m = s >> 5, g = s & 31;
    const uint4 v = *(const uint4*)(fl_b + m * 264 + g * 8);
    *(uint4*)(o1 + ((size_t)b * 1024 + m0 + m) * 512 + c0 + g * 8) = v;
  }
}

// ---------------------------------------------------------------------------
// K4: out[b][c][n] = g*(Wo @ o1^T + bo) + x.  M=c(512) N=n(1024) K=v(512)
// Residual path kept exact fp32.
__global__ __launch_bounds__(256) void k4_proj(
    const ushort_t* __restrict__ Wob, const ushort_t* __restrict__ o1,
    const float* __restrict__ bo, const float* __restrict__ gamma,
    const float* __restrict__ x, float* __restrict__ out)
{
  __shared__ __align__(16) ushort_t lds[128 * 136];
  const int b = blockIdx.z, m0 = blockIdx.y * 128, n0 = blockIdx.x * 128;
  f32x4 acc[4][4];
  gemm_core<128>(Wob, 512, o1 + (size_t)b * 524288, 512, 512, m0, n0,
                 lds, lds + 128 * 64, acc);
  const int t = threadIdx.x, lane = t & 63, quad = lane >> 4, l15 = lane & 15;
  const int w = t >> 6, wm = w >> 1, wn = w & 1;
  const float g = gamma[0];
  float br[4][4];
  #pragma unroll
  for (int i = 0; i < 4; ++i)
    #pragma unroll
    for (int r = 0; r < 4; ++r)
      br[i][r] = bo[m0 + wm * 64 + i * 16 + quad * 4 + r];
  float* fl = (float*)lds;  // 64 rows x 132 f stride
  #pragma unroll
  for (int h = 0; h < 2; ++h) {
    if (wm == h) {
      #pragma unroll
      for (int i = 0; i < 4; ++i)
        #pragma unroll
        for (int j = 0; j < 4; ++j)
          #pragma unroll
          for (int r = 0; r < 4; ++r)
            fl[(i * 16 + quad * 4 + r) * 132 + wn * 64 + j * 16 + l15] =
                g * (acc[i][j][r] + br[i][r]);
    }
    __syncthreads();
    #pragma unroll
    for (int i2 = 0; i2 < 8; ++i2) {
      const int s = i2 * 256 + t, m = s >> 5, c4 = s & 31;
      f32x4 v = *(const f32x4*)(fl + m * 132 + c4 * 4);
      const size_t gi = ((size_t)b * 512 + m0 + h * 64 + m) * 1024 + n0 + c4 * 4;
      const f32x4 xr = *(const f32x4*)(x + gi);
      v += xr;
      *(f32x4*)(out + gi) = v;
    }
    __syncthreads();
  }
}

// ---------------------------------------------------------------------------
extern "C" void kernel_launch(void* const* d_in, const int* in_sizes, int n_in,
                              void* d_out, int out_size, void* d_ws, size_t ws_size,
                              hipStream_t stream) {
  const float* x     = (const float*)d_in[0];
  const float* Wq    = (const float*)d_in[1];
  const float* bq    = (const float*)d_in[2];
  const float* Wk    = (const float*)d_in[3];
  const float* bk    = (const float*)d_in[4];
  const float* Wv    = (const float*)d_in[5];
  const float* bv    = (const float*)d_in[6];
  const float* Wo    = (const float*)d_in[7];
  const float* bo    = (const float*)d_in[8];
  const float* gamma = (const float*)d_in[9];
  float* out = (float*)d_out;

  char* wsp = (char*)d_ws;
  ushort_t* xbfT   = (ushort_t*)wsp;  wsp += (size_t)16 * 1024 * 512 * 2;  // 16 MB
  ushort_t* Wqk_bf = (ushort_t*)wsp;  wsp += (size_t)128 * 512 * 2;
  ushort_t* Wv_bf  = (ushort_t*)wsp;  wsp += (size_t)512 * 512 * 2;
  ushort_t* Wo_bf  = (ushort_t*)wsp;  wsp += (size_t)512 * 512 * 2;
  ushort_t* qkt    = (ushort_t*)wsp;  wsp += (size_t)16 * 1024 * 128 * 2;  // 4 MB
  ushort_t* vt2    = (ushort_t*)wsp;  wsp += (size_t)16 * 512 * 1024 * 2;  // 16 MB
  ushort_t* o1     = xbfT;  // xbfT dead after k1; reuse for o1

  prep_x    <<<dim3(16, 9, 16), 256, 0, stream>>>(x, Wq, Wk, Wv, Wo,
                                                  xbfT, Wqk_bf, Wv_bf, Wo_bf);
  k1_fused  <<<768, 256, 0, stream>>>(xbfT, Wqk_bf, Wv_bf, bq, bk, bv, qkt, vt2);
  flash_attn<<<dim3(2, 16, 16), 256, 0, stream>>>(qkt, vt2, o1);
  k4_proj   <<<dim3(8, 4, 16), 256, 0, stream>>>(Wo_bf, o1, bo, gamma, x, out);
}